// Round 1
// 439.359 us; speedup vs baseline: 1.0238x; 1.0238x over previous
//
#include <hip/hip_runtime.h>
#include <hip/hip_bf16.h>

typedef __bf16 bf16x8 __attribute__((ext_vector_type(8)));
typedef float  f32x4  __attribute__((ext_vector_type(4)));

#define DEVI __device__ __forceinline__

DEVI float bf2f(__hip_bfloat16 x) { return __bfloat162float(x); }
DEVI __hip_bfloat16 f2bf(float x) { return __float2bfloat16(x); }

DEVI f32x4 mfma16(bf16x8 a, bf16x8 b, f32x4 c) {
    return __builtin_amdgcn_mfma_f32_16x16x32_bf16(a, b, c, 0, 0, 0);
}

DEVI bf16x8 ld8(const __hip_bfloat16* p) {
    return *reinterpret_cast<const bf16x8*>(p);
}

// convert 8 contiguous fp32 -> bf16x8 fragment
DEVI bf16x8 cvt8(const float* p) {
    bf16x8 r;
#pragma unroll
    for (int i = 0; i < 8; ++i) r[i] = (__bf16)p[i];
    return r;
}

// ---------------------------------------------------------------------------
// Sizes: B=64, N=256, D=128, H=8, DK=16, FF=512.  All external I/O fp32.
// ---------------------------------------------------------------------------

// K0: repack fp32 weights into MFMA-B-friendly bf16 layouts (row = out col, contiguous k)
__global__ __launch_bounds__(256) void repack_kernel(
    const float* __restrict__ Wq, const float* __restrict__ Wk,
    const float* __restrict__ Wv, const float* __restrict__ W_out,
    const float* __restrict__ ff_w1, const float* __restrict__ ff_w2,
    __hip_bfloat16* __restrict__ Wqkvt, __hip_bfloat16* __restrict__ Wot,
    __hip_bfloat16* __restrict__ w1t, __hip_bfloat16* __restrict__ w2t)
{
    int t = blockIdx.x * 256 + threadIdx.x;
    if (t < 49152) {                       // Wqkvt[c][d], c = qkv*128 + h*16 + k
        int c = t >> 7, d = t & 127;
        int qkv = c >> 7, h = (c >> 4) & 7, k = c & 15;
        const float* W = (qkv == 0) ? Wq : (qkv == 1) ? Wk : Wv;
        Wqkvt[t] = f2bf(W[(h * 128 + d) * 16 + k]);
    } else if (t < 65536) {                // Wot[d][h*16+v] = W_out[h][v][d]
        int idx = t - 49152;
        int d = idx >> 7, hv = idx & 127, h = hv >> 4, v = hv & 15;
        Wot[idx] = f2bf(W_out[(h * 16 + v) * 128 + d]);
    } else if (t < 131072) {               // w1t[f][d] = ff_w1[d][f]
        int idx = t - 65536;
        int f = idx >> 7, d = idx & 127;
        w1t[idx] = f2bf(ff_w1[d * 512 + f]);
    } else {                               // w2t[d2][f] = ff_w2[f][d2]
        int idx = t - 131072;
        int d2 = idx >> 9, f = idx & 511;
        w2t[idx] = f2bf(ff_w2[f * 128 + d2]);
    }
}

// K1: QKV projection. [16384 x 128] @ [128 x 384] -> Q [b][h][n][k], K [b][h][m][k], Vt [b][h][k][m]
__global__ __launch_bounds__(512) void qkv_kernel(
    const float* __restrict__ hem, const __hip_bfloat16* __restrict__ Wqkvt,
    __hip_bfloat16* __restrict__ Qb, __hip_bfloat16* __restrict__ Kb,
    __hip_bfloat16* __restrict__ Vtb)
{
    const int w = threadIdx.x >> 6, lane = threadIdx.x & 63;
    const int quad = lane >> 4, col = lane & 15;
    const int row0 = blockIdx.x * 32;

    f32x4 acc[2][3] = {};
#pragma unroll
    for (int ks = 0; ks < 4; ++ks) {
        bf16x8 a[2], bb[3];
#pragma unroll
        for (int mt = 0; mt < 2; ++mt)
            a[mt] = cvt8(hem + (size_t)(row0 + mt * 16 + col) * 128 + ks * 32 + quad * 8);
#pragma unroll
        for (int nt = 0; nt < 3; ++nt) {
            int c = (w * 3 + nt) * 16 + col;
            bb[nt] = ld8(Wqkvt + (size_t)c * 128 + ks * 32 + quad * 8);
        }
#pragma unroll
        for (int mt = 0; mt < 2; ++mt)
#pragma unroll
            for (int nt = 0; nt < 3; ++nt)
                acc[mt][nt] = mfma16(a[mt], bb[nt], acc[mt][nt]);
    }
#pragma unroll
    for (int mt = 0; mt < 2; ++mt)
#pragma unroll
        for (int nt = 0; nt < 3; ++nt)
#pragma unroll
            for (int rg = 0; rg < 4; ++rg) {
                int row = row0 + mt * 16 + quad * 4 + rg;
                int c = (w * 3 + nt) * 16 + col;
                int qkv = c >> 7, h = (c >> 4) & 7, k = c & 15;
                int bb_ = row >> 8, n = row & 255;
                __hip_bfloat16 v = f2bf(acc[mt][nt][rg]);
                if (qkv == 0)      Qb[(((size_t)bb_ * 8 + h) * 256 + n) * 16 + k] = v;
                else if (qkv == 1) Kb[(((size_t)bb_ * 8 + h) * 256 + n) * 16 + k] = v;
                else               Vtb[(((size_t)bb_ * 8 + h) * 16 + k) * 256 + n] = v;
            }
}

// K2: fused attention. One block = (b, 4 rows n0..n0+3). 512 threads = 8 waves.
// v3: bank-conflict-free LDS layouts.
//   - scores/route split into two [1024][8] bf16 buffers (16-B rows, bank stride 4,
//     rb shifted +16 B so its bank base differs from sb by 4).
//   - route staged with per-lane SCALAR loads (rows walk at stride 1 -> 8-way max,
//     vs float4's stride-4 rows -> all-lanes-one-bank 64-way).
//   - P2 attn f32 output split 4+4 across sb/rb rows (conflict-free writes).
//   - softb padded to [272] (row stride 544 B == 8 dwords mod 32 -> conflict-free P4 reads).
//   - headsb padded to [144] (row stride 288 B -> P5 reads 4-way instead of 16-way).
__global__ __launch_bounds__(512) void attn_kernel_v3(
    const __hip_bfloat16* __restrict__ Qb, const __hip_bfloat16* __restrict__ Kb,
    const __hip_bfloat16* __restrict__ Vtb, const float* __restrict__ route,
    const float* __restrict__ sa_w1, const float* __restrict__ sa_b1,
    const float* __restrict__ sa_w2, const float* __restrict__ sa_b2,
    const float* __restrict__ h_em, const __hip_bfloat16* __restrict__ Wot,
    float* __restrict__ y, float* __restrict__ out)
{
    __shared__ alignas(16) __hip_bfloat16 srb[2 * 1024 * 8 + 8];  // sb | 16B pad | rb
    __shared__ alignas(16) __hip_bfloat16 softb[8][4][272];
    __shared__ alignas(16) __hip_bfloat16 headsb[16][144];
    __shared__ alignas(16) __hip_bfloat16 saw1t[16][32];
    __shared__ alignas(16) __hip_bfloat16 saw2t[16][32];
    __shared__ float b1s[16], b2s[16];
    __hip_bfloat16* sb = srb;               // [1024][8] scores (ch 0..7), later attn h 0..3 (f32)
    __hip_bfloat16* rb = srb + 8192 + 8;    // [1024][8] route  (ch 8..15), later attn h 4..7 (f32)

    const int tid = threadIdx.x;
    const int w = tid >> 6, lane = tid & 63, quad = lane >> 4, col = lane & 15;
    const int b = blockIdx.x >> 6, tile = blockIdx.x & 63, n0 = tile * 4;
    const f32x4 zero = {0.f, 0.f, 0.f, 0.f};

    {   // P0: stage score_aggr weights (transposed, zero-padded to K=32)
        int o = tid >> 5, i = tid & 31;
        saw1t[o][i] = (i < 16) ? f2bf(sa_w1[i * 16 + o]) : f2bf(0.f);
        saw2t[o][i] = (i < 16 && o < 8) ? f2bf(sa_w2[i * 8 + o]) : f2bf(0.f);
        if (tid < 16) {
            b1s[tid] = sa_b1[tid];
            b2s[tid] = (tid < 8) ? sa_b2[tid] : 0.f;
        }
    }

    {   // P1: route prefetch (scalar, stride-64 per j) + scores + route copy/stage
        const int h = w;
        const size_t rbase = (((size_t)h * 64 + b) * 256 + n0) * 256;
        const float* rsrc = route + rbase;
        float rv[16];
#pragma unroll
        for (int r = 0; r < 4; ++r)
#pragma unroll
            for (int j = 0; j < 4; ++j)
                rv[r * 4 + j] = rsrc[r * 256 + j * 64 + lane];

        const __hip_bfloat16* Qh = Qb + ((size_t)(b * 8 + h)) * 256 * 16;
        const __hip_bfloat16* Kh = Kb + ((size_t)(b * 8 + h)) * 256 * 16;
        bf16x8 aq = ld8(Qh + (size_t)(n0 + (col & 3)) * 16 + (quad & 1) * 8);
#pragma unroll
        for (int nt = 0; nt < 16; ++nt) {
            bf16x8 bk = {};
            if (quad < 2) bk = ld8(Kh + (size_t)(nt * 16 + col) * 16 + quad * 8);
            f32x4 c = mfma16(aq, bk, zero);
            if (quad == 0) {
#pragma unroll
                for (int rg = 0; rg < 4; ++rg)
                    sb[(rg * 256 + nt * 16 + col) * 8 + h] = f2bf(c[rg]);
            }
        }
        float* rdst = out + 2097152 + rbase;
#pragma unroll
        for (int r = 0; r < 4; ++r)
#pragma unroll
            for (int j = 0; j < 4; ++j) {
                int nm = r * 256 + j * 64 + lane;
                float v = rv[r * 4 + j];
                rdst[nm] = v;                 // fp32 passthrough copy (exact)
                rb[nm * 8 + h] = f2bf(v);     // stage transposed: rows walk stride-1
            }
    }
    __syncthreads();

    {   // P2: score_aggr (2x MFMA over channel dim; tiles are wave-private)
        bf16x8 bw1 = *(const bf16x8*)&saw1t[col][quad * 8];
        bf16x8 bw2 = *(const bf16x8*)&saw2t[col][quad * 8];
        float bias1 = b1s[col], bias2 = b2s[col];
        float* sbf = reinterpret_cast<float*>(sb);
        float* rbf = reinterpret_cast<float*>(rb);
        const __hip_bfloat16* arow = (quad & 1) ? rb : sb;   // quad0/2: k0-7, quad1/3: k8-15
#pragma unroll
        for (int t8 = 0; t8 < 8; ++t8) {
            int nm0 = (w * 8 + t8) * 16;
            bf16x8 a = *(const bf16x8*)&arow[(nm0 + col) * 8];
            f32x4 h1 = mfma16(a, bw1, zero);
#pragma unroll
            for (int rg = 0; rg < 4; ++rg) {
                int nm = nm0 + quad * 4 + rg;
                __hip_bfloat16 hv = f2bf(fmaxf(h1[rg] + bias1, 0.f));
                if (col < 8) sb[nm * 8 + col] = hv;
                else         rb[nm * 8 + (col - 8)] = hv;
            }
            __asm__ volatile("s_waitcnt lgkmcnt(0)" ::: "memory");
            bf16x8 a2 = *(const bf16x8*)&arow[(nm0 + col) * 8];
            f32x4 h2 = mfma16(a2, bw2, zero);
            if (col < 8) {
#pragma unroll
                for (int rg = 0; rg < 4; ++rg) {
                    int nm = nm0 + quad * 4 + rg;
                    float av = h2[rg] + bias2;
                    if (col < 4) sbf[nm * 4 + col] = av;         // attn h 0..3
                    else         rbf[nm * 4 + (col - 4)] = av;   // attn h 4..7
                }
            }
            __asm__ volatile("s_waitcnt lgkmcnt(0)" ::: "memory");
        }
    }
    __syncthreads();

    {   // P3: softmax over m for each (h=w, r); write soft bf16
        const float* src = (w < 4) ? reinterpret_cast<const float*>(sb)
                                   : reinterpret_cast<const float*>(rb);
        const int c = w & 3;
#pragma unroll
        for (int r = 0; r < 4; ++r) {
            float vv[4];
#pragma unroll
            for (int j = 0; j < 4; ++j) vv[j] = src[(r * 256 + j * 64 + lane) * 4 + c];
            float mx = fmaxf(fmaxf(vv[0], vv[1]), fmaxf(vv[2], vv[3]));
#pragma unroll
            for (int off = 32; off; off >>= 1) mx = fmaxf(mx, __shfl_xor(mx, off, 64));
            float e[4], s = 0.f;
#pragma unroll
            for (int j = 0; j < 4; ++j) { e[j] = __expf(vv[j] - mx); s += e[j]; }
#pragma unroll
            for (int off = 32; off; off >>= 1) s += __shfl_xor(s, off, 64);
            float inv = 1.f / s;
#pragma unroll
            for (int j = 0; j < 4; ++j) softb[w][r][j * 64 + lane] = f2bf(e[j] * inv);
        }
    }
    __syncthreads();

    {   // P4: PV (wave w <-> head h=w)
        const int h = w;
        f32x4 acc = zero;
        const __hip_bfloat16* Vh = Vtb + ((size_t)(b * 8 + h)) * 16 * 256;
#pragma unroll
        for (int ks = 0; ks < 8; ++ks) {
            bf16x8 a = *(const bf16x8*)&softb[h][col & 3][ks * 32 + quad * 8];
            bf16x8 bv = ld8(Vh + (size_t)col * 256 + ks * 32 + quad * 8);
            acc = mfma16(a, bv, acc);
        }
        if (quad == 0) {
#pragma unroll
            for (int rg = 0; rg < 4; ++rg)
                headsb[rg][h * 16 + col] = f2bf(acc[rg]);
        }
    }
    __syncthreads();

    {   // P5: out-proj + residual -> y (fp32). wave w owns d-tile [w*16, w*16+16)
        f32x4 acc = zero;
#pragma unroll
        for (int ks = 0; ks < 4; ++ks) {
            bf16x8 a = *(const bf16x8*)&headsb[col][ks * 32 + quad * 8];
            bf16x8 bo = ld8(Wot + (size_t)(w * 16 + col) * 128 + ks * 32 + quad * 8);
            acc = mfma16(a, bo, acc);
        }
        if (quad == 0) {
#pragma unroll
            for (int rg = 0; rg < 4; ++rg) {
                int n = n0 + rg, d = w * 16 + col;
                size_t idx = ((size_t)b * 256 + n) * 128 + d;
                y[idx] = acc[rg] + h_em[idx];
            }
        }
    }
}

// output store helpers for the LN template
DEVI void stout(float* p, float v) { *p = v; }
DEVI void stout(__hip_bfloat16* p, float v) { *p = f2bf(v); }

// K3/K5: per-batch LayerNorm over (n,d) = 32768 elements, unbiased var (/32767)
template<typename OUT>
__global__ __launch_bounds__(1024) void ln_kernel(
    const float* __restrict__ y, OUT* __restrict__ out)
{
    const int b = blockIdx.x;
    const float* yb = y + (size_t)b * 32768;
    float v[32], s = 0.f, sq = 0.f;
#pragma unroll
    for (int j = 0; j < 32; ++j) {
        float x = yb[threadIdx.x + 1024 * j];
        v[j] = x; s += x; sq += x * x;
    }
#pragma unroll
    for (int off = 32; off; off >>= 1) {
        s += __shfl_down(s, off, 64);
        sq += __shfl_down(sq, off, 64);
    }
    __shared__ float ps[16], pq[16], stats[2];
    int wv = threadIdx.x >> 6, ln = threadIdx.x & 63;
    if (ln == 0) { ps[wv] = s; pq[wv] = sq; }
    __syncthreads();
    if (threadIdx.x < 64) {
        float a = (ln < 16) ? ps[ln] : 0.f;
        float bq = (ln < 16) ? pq[ln] : 0.f;
#pragma unroll
        for (int off = 8; off; off >>= 1) {
            a += __shfl_down(a, off, 64);
            bq += __shfl_down(bq, off, 64);
        }
        if (ln == 0) {
            float mean = a * (1.f / 32768.f);
            float var = fmaxf((bq - 32768.f * mean * mean) * (1.f / 32767.f), 0.f);
            stats[0] = mean;
            stats[1] = rsqrtf(var + 1e-5f);
        }
    }
    __syncthreads();
    float mean = stats[0], rstd = stats[1];
    OUT* ob = out + (size_t)b * 32768;
#pragma unroll
    for (int j = 0; j < 32; ++j)
        stout(ob + threadIdx.x + 1024 * j, (v[j] - mean) * rstd);
}

// K4: fused FF: y = relu(x @ w1) @ w2 + x, hidden tile lives in LDS only
__global__ __launch_bounds__(512) void ff_kernel(
    const __hip_bfloat16* __restrict__ xb, const __hip_bfloat16* __restrict__ w1t,
    const __hip_bfloat16* __restrict__ w2t, float* __restrict__ y)
{
    __shared__ alignas(16) __hip_bfloat16 hid[64][512];   // 64 KB
    const int w = threadIdx.x >> 6, lane = threadIdx.x & 63;
    const int quad = lane >> 4, col = lane & 15;
    const int r0 = blockIdx.x * 64;

    f32x4 acc[4][4] = {};
#pragma unroll
    for (int ks = 0; ks < 4; ++ks) {
        bf16x8 a[4], bb[4];
#pragma unroll
        for (int mt = 0; mt < 4; ++mt)
            a[mt] = ld8(xb + (size_t)(r0 + mt * 16 + col) * 128 + ks * 32 + quad * 8);
#pragma unroll
        for (int nt = 0; nt < 4; ++nt) {
            int f = (w * 4 + nt) * 16 + col;
            bb[nt] = ld8(w1t + (size_t)f * 128 + ks * 32 + quad * 8);
        }
#pragma unroll
        for (int mt = 0; mt < 4; ++mt)
#pragma unroll
            for (int nt = 0; nt < 4; ++nt)
                acc[mt][nt] = mfma16(a[mt], bb[nt], acc[mt][nt]);
    }
#pragma unroll
    for (int mt = 0; mt < 4; ++mt)
#pragma unroll
        for (int nt = 0; nt < 4; ++nt)
#pragma unroll
            for (int rg = 0; rg < 4; ++rg) {
                int row = mt * 16 + quad * 4 + rg;
                int f = (w * 4 + nt) * 16 + col;
                hid[row][f] = f2bf(fmaxf(acc[mt][nt][rg], 0.f));
            }
    __syncthreads();

    f32x4 acc2[4] = {};
#pragma unroll
    for (int ks = 0; ks < 16; ++ks) {
        bf16x8 bb = ld8(w2t + (size_t)(w * 16 + col) * 512 + ks * 32 + quad * 8);
#pragma unroll
        for (int mt = 0; mt < 4; ++mt) {
            bf16x8 a = *(const bf16x8*)&hid[mt * 16 + col][ks * 32 + quad * 8];
            acc2[mt] = mfma16(a, bb, acc2[mt]);
        }
    }
#pragma unroll
    for (int mt = 0; mt < 4; ++mt)
#pragma unroll
        for (int rg = 0; rg < 4; ++rg) {
            int row = r0 + mt * 16 + quad * 4 + rg;
            int d = w * 16 + col;
            size_t idx = (size_t)row * 128 + d;
            y[idx] = acc2[mt][rg] + bf2f(xb[idx]);
        }
}

extern "C" void kernel_launch(void* const* d_in, const int* in_sizes, int n_in,
                              void* d_out, int out_size, void* d_ws, size_t ws_size,
                              hipStream_t stream)
{
    const float* h_em  = (const float*)d_in[0];
    const float* route = (const float*)d_in[1];
    const float* Wq    = (const float*)d_in[2];
    const float* Wk    = (const float*)d_in[3];
    const float* Wv    = (const float*)d_in[4];
    const float* W_out = (const float*)d_in[5];
    const float* sa_w1 = (const float*)d_in[6];
    const float* sa_b1 = (const float*)d_in[7];
    const float* sa_w2 = (const float*)d_in[8];
    const float* sa_b2 = (const float*)d_in[9];
    const float* ff_w1 = (const float*)d_in[10];
    const float* ff_w2 = (const float*)d_in[11];

    char* ws = (char*)d_ws;
    __hip_bfloat16* Qb    = (__hip_bfloat16*)(ws);
    __hip_bfloat16* Kb    = (__hip_bfloat16*)(ws + 4194304);
    __hip_bfloat16* Vtb   = (__hip_bfloat16*)(ws + 8388608);
    __hip_bfloat16* Wqkvt = (__hip_bfloat16*)(ws + 12582912);
    __hip_bfloat16* Wot   = (__hip_bfloat16*)(ws + 12681216);
    __hip_bfloat16* w1t   = (__hip_bfloat16*)(ws + 12713984);
    __hip_bfloat16* w2t   = (__hip_bfloat16*)(ws + 12845056);
    float*          yv    = (float*)(ws + 12976128);
    __hip_bfloat16* xb    = (__hip_bfloat16*)(ws + 21364736);

    hipLaunchKernelGGL(repack_kernel, dim3(768), dim3(256), 0, stream,
                       Wq, Wk, Wv, W_out, ff_w1, ff_w2, Wqkvt, Wot, w1t, w2t);
    hipLaunchKernelGGL(qkv_kernel, dim3(512), dim3(512), 0, stream,
                       h_em, Wqkvt, Qb, Kb, Vtb);
    hipLaunchKernelGGL(attn_kernel_v3, dim3(4096), dim3(512), 0, stream,
                       Qb, Kb, Vtb, route, sa_w1, sa_b1, sa_w2, sa_b2, h_em, Wot,
                       yv, (float*)d_out);
    hipLaunchKernelGGL(ln_kernel<__hip_bfloat16>, dim3(64), dim3(1024), 0, stream, yv, xb);
    hipLaunchKernelGGL(ff_kernel, dim3(256), dim3(512), 0, stream, xb, w1t, w2t, yv);
    hipLaunchKernelGGL(ln_kernel<float>, dim3(64), dim3(1024), 0, stream,
                       yv, (float*)d_out);
}

// Round 2
// 375.613 us; speedup vs baseline: 1.1976x; 1.1697x over previous
//
#include <hip/hip_runtime.h>
#include <hip/hip_bf16.h>

typedef __bf16 bf16x8 __attribute__((ext_vector_type(8)));
typedef float  f32x4  __attribute__((ext_vector_type(4)));

#define DEVI __device__ __forceinline__

DEVI float bf2f(__hip_bfloat16 x) { return __bfloat162float(x); }
DEVI __hip_bfloat16 f2bf(float x) { return __float2bfloat16(x); }

DEVI f32x4 mfma16(bf16x8 a, bf16x8 b, f32x4 c) {
    return __builtin_amdgcn_mfma_f32_16x16x32_bf16(a, b, c, 0, 0, 0);
}

DEVI bf16x8 ld8(const __hip_bfloat16* p) {
    return *reinterpret_cast<const bf16x8*>(p);
}

// convert 8 contiguous fp32 -> bf16x8 fragment
DEVI bf16x8 cvt8(const float* p) {
    bf16x8 r;
#pragma unroll
    for (int i = 0; i < 8; ++i) r[i] = (__bf16)p[i];
    return r;
}

// pack two f32 -> one u32 of 2 bf16 (lo = a, hi = b), RNE
DEVI unsigned cvtpk(float a, float b) {
    unsigned r;
    asm("v_cvt_pk_bf16_f32 %0, %1, %2" : "=v"(r) : "v"(a), "v"(b));
    return r;
}

DEVI bf16x8 u4bf(unsigned x0, unsigned x1, unsigned x2, unsigned x3) {
    union { unsigned u[4]; bf16x8 b; } cv;
    cv.u[0] = x0; cv.u[1] = x1; cv.u[2] = x2; cv.u[3] = x3;
    return cv.b;
}

// ---------------------------------------------------------------------------
// Sizes: B=64, N=256, D=128, H=8, DK=16, FF=512.  All external I/O fp32.
// ---------------------------------------------------------------------------

// K0: repack fp32 weights into MFMA-B-friendly bf16 layouts (row = out col, contiguous k)
__global__ __launch_bounds__(256) void repack_kernel(
    const float* __restrict__ Wq, const float* __restrict__ Wk,
    const float* __restrict__ Wv, const float* __restrict__ W_out,
    const float* __restrict__ ff_w1, const float* __restrict__ ff_w2,
    __hip_bfloat16* __restrict__ Wqkvt, __hip_bfloat16* __restrict__ Wot,
    __hip_bfloat16* __restrict__ w1t, __hip_bfloat16* __restrict__ w2t)
{
    int t = blockIdx.x * 256 + threadIdx.x;
    if (t < 49152) {                       // Wqkvt[c][d], c = qkv*128 + h*16 + k
        int c = t >> 7, d = t & 127;
        int qkv = c >> 7, h = (c >> 4) & 7, k = c & 15;
        const float* W = (qkv == 0) ? Wq : (qkv == 1) ? Wk : Wv;
        Wqkvt[t] = f2bf(W[(h * 128 + d) * 16 + k]);
    } else if (t < 65536) {                // Wot[d][h*16+v] = W_out[h][v][d]
        int idx = t - 49152;
        int d = idx >> 7, hv = idx & 127, h = hv >> 4, v = hv & 15;
        Wot[idx] = f2bf(W_out[(h * 16 + v) * 128 + d]);
    } else if (t < 131072) {               // w1t[f][d] = ff_w1[d][f]
        int idx = t - 65536;
        int f = idx >> 7, d = idx & 127;
        w1t[idx] = f2bf(ff_w1[d * 512 + f]);
    } else {                               // w2t[d2][f] = ff_w2[f][d2]
        int idx = t - 131072;
        int d2 = idx >> 9, f = idx & 511;
        w2t[idx] = f2bf(ff_w2[f * 128 + d2]);
    }
}

// K1: QKV projection. [16384 x 128] @ [128 x 384] -> Q [b][h][n][k], K [b][h][m][k], Vt [b][h][k][m]
__global__ __launch_bounds__(512) void qkv_kernel(
    const float* __restrict__ hem, const __hip_bfloat16* __restrict__ Wqkvt,
    __hip_bfloat16* __restrict__ Qb, __hip_bfloat16* __restrict__ Kb,
    __hip_bfloat16* __restrict__ Vtb)
{
    const int w = threadIdx.x >> 6, lane = threadIdx.x & 63;
    const int quad = lane >> 4, col = lane & 15;
    const int row0 = blockIdx.x * 32;

    f32x4 acc[2][3] = {};
#pragma unroll
    for (int ks = 0; ks < 4; ++ks) {
        bf16x8 a[2], bb[3];
#pragma unroll
        for (int mt = 0; mt < 2; ++mt)
            a[mt] = cvt8(hem + (size_t)(row0 + mt * 16 + col) * 128 + ks * 32 + quad * 8);
#pragma unroll
        for (int nt = 0; nt < 3; ++nt) {
            int c = (w * 3 + nt) * 16 + col;
            bb[nt] = ld8(Wqkvt + (size_t)c * 128 + ks * 32 + quad * 8);
        }
#pragma unroll
        for (int mt = 0; mt < 2; ++mt)
#pragma unroll
            for (int nt = 0; nt < 3; ++nt)
                acc[mt][nt] = mfma16(a[mt], bb[nt], acc[mt][nt]);
    }
#pragma unroll
    for (int mt = 0; mt < 2; ++mt)
#pragma unroll
        for (int nt = 0; nt < 3; ++nt)
#pragma unroll
            for (int rg = 0; rg < 4; ++rg) {
                int row = row0 + mt * 16 + quad * 4 + rg;
                int c = (w * 3 + nt) * 16 + col;
                int qkv = c >> 7, h = (c >> 4) & 7, k = c & 15;
                int bb_ = row >> 8, n = row & 255;
                __hip_bfloat16 v = f2bf(acc[mt][nt][rg]);
                if (qkv == 0)      Qb[(((size_t)bb_ * 8 + h) * 256 + n) * 16 + k] = v;
                else if (qkv == 1) Kb[(((size_t)bb_ * 8 + h) * 256 + n) * 16 + k] = v;
                else               Vtb[(((size_t)bb_ * 8 + h) * 16 + k) * 256 + n] = v;
            }
}

// K2 v4: fused attention. One block = (b, 8 rows n0..n0+7). 512 threads = 8 waves.
// Structure: grid 2048 (was 4096), transposed score_aggr MLP (hidden stays in
// registers via cvt_pk+shfl, zero lgkmcnt drains), in-place softmax output with
// XOR swizzle, 4 barriers total.
//   - sb/rb: two [2048][8ch] bf16 buffers (scores h0-7 / route h0-7), 16-B rows.
//     In P2, logits overwrite them in-place as f32 [nm][4c] (wave+lane-private rows).
//     In P3, soft bf16 [h][n][m^swz] overwrites sb (wave-private slabs).
//   - P2: wave w owns n-row w (all 256 m). MFMA1: A=w1^T, B=st-rows ->
//     C1[ch][nm]; relu+pack in regs; 4 shfls build MFMA2's B frag; MFMA2:
//     A=w2^T -> C2[head][nm]; single f32 write per value. No intermediate LDS.
__global__ __launch_bounds__(512) void attn_kernel_v4(
    const __hip_bfloat16* __restrict__ Qb, const __hip_bfloat16* __restrict__ Kb,
    const __hip_bfloat16* __restrict__ Vtb, const float* __restrict__ route,
    const float* __restrict__ sa_w1, const float* __restrict__ sa_b1,
    const float* __restrict__ sa_w2, const float* __restrict__ sa_b2,
    const float* __restrict__ h_em, const __hip_bfloat16* __restrict__ Wot,
    float* __restrict__ y, float* __restrict__ out)
{
    __shared__ alignas(16) __hip_bfloat16 srb[2 * 2048 * 8 + 8];  // sb | 16B pad | rb
    __shared__ alignas(16) __hip_bfloat16 headsb[8][144];
    __shared__ alignas(16) __hip_bfloat16 saw1t[16][32];
    __shared__ alignas(16) __hip_bfloat16 saw2t[16][32];
    __shared__ float b1s[16], b2s[16];
    __hip_bfloat16* sb = srb;                // [2048][8] scores ch0-7
    __hip_bfloat16* rb = srb + 16384 + 8;    // [2048][8] route  ch8-15
    float* sbf = reinterpret_cast<float*>(sb);   // logits heads 0-3, [nm][4]
    float* rbf = reinterpret_cast<float*>(rb);   // logits heads 4-7, [nm][4]

    const int tid = threadIdx.x;
    const int w = tid >> 6, lane = tid & 63, quad = lane >> 4, col = lane & 15;
    const int b = blockIdx.x >> 5, tile = blockIdx.x & 31, n0 = tile * 8;
    const f32x4 zero = {0.f, 0.f, 0.f, 0.f};

    {   // P0: stage score_aggr weights (transposed, zero-padded to K=32)
        int o = tid >> 5, i = tid & 31;
        saw1t[o][i] = (i < 16) ? f2bf(sa_w1[i * 16 + o]) : f2bf(0.f);
        saw2t[o][i] = (i < 16 && o < 8) ? f2bf(sa_w2[i * 8 + o]) : f2bf(0.f);
        if (tid < 16) {
            b1s[tid] = sa_b1[tid];
            b2s[tid] = (tid < 8) ? sa_b2[tid] : 0.f;
        }
    }

    {   // P1: route prefetch (scalar) + QK^T scores + route copy/stage
        const int h = w;
        const size_t rbase = (((size_t)h * 64 + b) * 256 + n0) * 256;
        const float* rsrc = route + rbase;
        float rv[32];
#pragma unroll
        for (int r = 0; r < 8; ++r)
#pragma unroll
            for (int j = 0; j < 4; ++j)
                rv[r * 4 + j] = rsrc[r * 256 + j * 64 + lane];

        const __hip_bfloat16* Qh = Qb + ((size_t)(b * 8 + h)) * 256 * 16;
        const __hip_bfloat16* Kh = Kb + ((size_t)(b * 8 + h)) * 256 * 16;
        bf16x8 aq = ld8(Qh + (size_t)(n0 + (col & 7)) * 16 + (quad & 1) * 8);
#pragma unroll
        for (int nt = 0; nt < 16; ++nt) {
            bf16x8 bk = {};
            if (quad < 2) bk = ld8(Kh + (size_t)(nt * 16 + col) * 16 + quad * 8);
            f32x4 c = mfma16(aq, bk, zero);
            if (quad < 2) {
#pragma unroll
                for (int rg = 0; rg < 4; ++rg)
                    sb[((quad * 4 + rg) * 256 + nt * 16 + col) * 8 + h] = f2bf(c[rg]);
            }
        }
        float* rdst = out + 2097152 + rbase;
#pragma unroll
        for (int r = 0; r < 8; ++r)
#pragma unroll
            for (int j = 0; j < 4; ++j) {
                int nm = r * 256 + j * 64 + lane;
                float v = rv[r * 4 + j];
                rdst[nm] = v;                 // fp32 passthrough copy (exact)
                rb[nm * 8 + h] = f2bf(v);     // stage transposed: rows walk stride-1
            }
    }
    __syncthreads();

    {   // P2: score_aggr, transposed (hidden in regs; no drains; 1-deep prefetch)
        bf16x8 a1 = ld8(&saw1t[col][quad * 8]);
        bf16x8 a2 = ld8(&saw2t[col][quad * 8]);
        f32x4 bv1 = *(const f32x4*)&b1s[quad * 4];
        f32x4 bv2 = *(const f32x4*)&b2s[quad * 4];
        const __hip_bfloat16* arow = (quad & 1) ? rb : sb;
        float* dstf = quad ? rbf : sbf;      // only quads 0 (h0-3) and 1 (h4-7) write
        const int rowbase = w * 256 + col;
        const int src0 = (lane & 15) + ((lane >> 4) & 1) * 32;

        bf16x8 b1 = ld8(&arow[(size_t)rowbase * 8]);
#pragma unroll
        for (int t8 = 0; t8 < 16; ++t8) {
            f32x4 c1 = mfma16(a1, b1, zero);
            bf16x8 b1n = b1;
            if (t8 < 15) b1n = ld8(&arow[(size_t)(rowbase + (t8 + 1) * 16) * 8]);
            unsigned p0 = cvtpk(fmaxf(c1[0] + bv1[0], 0.f), fmaxf(c1[1] + bv1[1], 0.f));
            unsigned p1 = cvtpk(fmaxf(c1[2] + bv1[2], 0.f), fmaxf(c1[3] + bv1[3], 0.f));
            unsigned x0 = __shfl((int)p0, src0, 64);
            unsigned x1 = __shfl((int)p1, src0, 64);
            unsigned x2 = __shfl((int)p0, src0 + 16, 64);
            unsigned x3 = __shfl((int)p1, src0 + 16, 64);
            bf16x8 b2 = u4bf(x0, x1, x2, x3);
            f32x4 c2 = mfma16(a2, b2, zero);
            if (quad < 2) {
                int base = (w * 256 + t8 * 16 + col) * 4;
#pragma unroll
                for (int rg = 0; rg < 4; ++rg)
                    dstf[base + rg] = c2[rg] + bv2[rg];
            }
            b1 = b1n;
        }
    }
    __syncthreads();

    float vv[32];
    {   // P3a: read all logits for (h=w, r=0..7) into registers
        const float* src = (w < 4) ? sbf : rbf;
        const int c = w & 3;
#pragma unroll
        for (int r = 0; r < 8; ++r)
#pragma unroll
            for (int j = 0; j < 4; ++j)
                vv[r * 4 + j] = src[(r * 256 + j * 64 + lane) * 4 + c];
    }
    __syncthreads();

    {   // P3b: softmax per (h=w, r); write soft bf16 in-place over sb, XOR-swizzled
        char* softw = (char*)srb + w * 4096;
#pragma unroll
        for (int r = 0; r < 8; ++r) {
            float v0 = vv[r * 4], v1 = vv[r * 4 + 1], v2 = vv[r * 4 + 2], v3 = vv[r * 4 + 3];
            float mx = fmaxf(fmaxf(v0, v1), fmaxf(v2, v3));
#pragma unroll
            for (int off = 32; off; off >>= 1) mx = fmaxf(mx, __shfl_xor(mx, off, 64));
            float e0 = __expf(v0 - mx), e1 = __expf(v1 - mx);
            float e2 = __expf(v2 - mx), e3 = __expf(v3 - mx);
            float s = e0 + e1 + e2 + e3;
#pragma unroll
            for (int off = 32; off; off >>= 1) s += __shfl_xor(s, off, 64);
            float inv = 1.f / s;
            char* rowp = softw + r * 512;
            const int swz = r << 4;
            *(__hip_bfloat16*)(rowp + (((0 * 64 + lane) * 2) ^ swz)) = f2bf(e0 * inv);
            *(__hip_bfloat16*)(rowp + (((1 * 64 + lane) * 2) ^ swz)) = f2bf(e1 * inv);
            *(__hip_bfloat16*)(rowp + (((2 * 64 + lane) * 2) ^ swz)) = f2bf(e2 * inv);
            *(__hip_bfloat16*)(rowp + (((3 * 64 + lane) * 2) ^ swz)) = f2bf(e3 * inv);
        }
    }
    // no barrier: wave w reads exactly the soft slab it wrote

    {   // P4: PV (wave w <-> head h=w), soft read through the same swizzle
        const int h = w;
        f32x4 acc = zero;
        const __hip_bfloat16* Vh = Vtb + ((size_t)(b * 8 + h)) * 16 * 256;
        const char* softh = (const char*)srb + h * 4096 + (col & 7) * 512;
        const int sx = (col & 7) << 4;
#pragma unroll
        for (int ks = 0; ks < 8; ++ks) {
            bf16x8 a = *(const bf16x8*)(softh + ((ks * 64 + quad * 16) ^ sx));
            bf16x8 bv = ld8(Vh + (size_t)col * 256 + ks * 32 + quad * 8);
            acc = mfma16(a, bv, acc);
        }
        if (quad < 2) {
#pragma unroll
            for (int rg = 0; rg < 4; ++rg)
                headsb[quad * 4 + rg][h * 16 + col] = f2bf(acc[rg]);
        }
    }
    __syncthreads();

    {   // P5: out-proj + residual -> y (fp32). wave w owns d-tile [w*16, w*16+16)
        f32x4 acc = zero;
#pragma unroll
        for (int ks = 0; ks < 4; ++ks) {
            bf16x8 a = *(const bf16x8*)&headsb[col & 7][ks * 32 + quad * 8];
            bf16x8 bo = ld8(Wot + (size_t)(w * 16 + col) * 128 + ks * 32 + quad * 8);
            acc = mfma16(a, bo, acc);
        }
        if (quad < 2) {
#pragma unroll
            for (int rg = 0; rg < 4; ++rg) {
                int n = n0 + quad * 4 + rg, d = w * 16 + col;
                size_t idx = ((size_t)b * 256 + n) * 128 + d;
                y[idx] = acc[rg] + h_em[idx];
            }
        }
    }
}

// output store helpers for the LN template
DEVI void stout(float* p, float v) { *p = v; }
DEVI void stout(__hip_bfloat16* p, float v) { *p = f2bf(v); }

// K3/K5: per-batch LayerNorm over (n,d) = 32768 elements, unbiased var (/32767)
template<typename OUT>
__global__ __launch_bounds__(1024) void ln_kernel(
    const float* __restrict__ y, OUT* __restrict__ out)
{
    const int b = blockIdx.x;
    const float* yb = y + (size_t)b * 32768;
    float v[32], s = 0.f, sq = 0.f;
#pragma unroll
    for (int j = 0; j < 32; ++j) {
        float x = yb[threadIdx.x + 1024 * j];
        v[j] = x; s += x; sq += x * x;
    }
#pragma unroll
    for (int off = 32; off; off >>= 1) {
        s += __shfl_down(s, off, 64);
        sq += __shfl_down(sq, off, 64);
    }
    __shared__ float ps[16], pq[16], stats[2];
    int wv = threadIdx.x >> 6, ln = threadIdx.x & 63;
    if (ln == 0) { ps[wv] = s; pq[wv] = sq; }
    __syncthreads();
    if (threadIdx.x < 64) {
        float a = (ln < 16) ? ps[ln] : 0.f;
        float bq = (ln < 16) ? pq[ln] : 0.f;
#pragma unroll
        for (int off = 8; off; off >>= 1) {
            a += __shfl_down(a, off, 64);
            bq += __shfl_down(bq, off, 64);
        }
        if (ln == 0) {
            float mean = a * (1.f / 32768.f);
            float var = fmaxf((bq - 32768.f * mean * mean) * (1.f / 32767.f), 0.f);
            stats[0] = mean;
            stats[1] = rsqrtf(var + 1e-5f);
        }
    }
    __syncthreads();
    float mean = stats[0], rstd = stats[1];
    OUT* ob = out + (size_t)b * 32768;
#pragma unroll
    for (int j = 0; j < 32; ++j)
        stout(ob + threadIdx.x + 1024 * j, (v[j] - mean) * rstd);
}

// K4: fused FF: y = relu(x @ w1) @ w2 + x, hidden tile lives in LDS only
__global__ __launch_bounds__(512) void ff_kernel(
    const __hip_bfloat16* __restrict__ xb, const __hip_bfloat16* __restrict__ w1t,
    const __hip_bfloat16* __restrict__ w2t, float* __restrict__ y)
{
    __shared__ alignas(16) __hip_bfloat16 hid[64][512];   // 64 KB
    const int w = threadIdx.x >> 6, lane = threadIdx.x & 63;
    const int quad = lane >> 4, col = lane & 15;
    const int r0 = blockIdx.x * 64;

    f32x4 acc[4][4] = {};
#pragma unroll
    for (int ks = 0; ks < 4; ++ks) {
        bf16x8 a[4], bb[4];
#pragma unroll
        for (int mt = 0; mt < 4; ++mt)
            a[mt] = ld8(xb + (size_t)(r0 + mt * 16 + col) * 128 + ks * 32 + quad * 8);
#pragma unroll
        for (int nt = 0; nt < 4; ++nt) {
            int f = (w * 4 + nt) * 16 + col;
            bb[nt] = ld8(w1t + (size_t)f * 128 + ks * 32 + quad * 8);
        }
#pragma unroll
        for (int mt = 0; mt < 4; ++mt)
#pragma unroll
            for (int nt = 0; nt < 4; ++nt)
                acc[mt][nt] = mfma16(a[mt], bb[nt], acc[mt][nt]);
    }
#pragma unroll
    for (int mt = 0; mt < 4; ++mt)
#pragma unroll
        for (int nt = 0; nt < 4; ++nt)
#pragma unroll
            for (int rg = 0; rg < 4; ++rg) {
                int row = mt * 16 + quad * 4 + rg;
                int f = (w * 4 + nt) * 16 + col;
                hid[row][f] = f2bf(fmaxf(acc[mt][nt][rg], 0.f));
            }
    __syncthreads();

    f32x4 acc2[4] = {};
#pragma unroll
    for (int ks = 0; ks < 16; ++ks) {
        bf16x8 bb = ld8(w2t + (size_t)(w * 16 + col) * 512 + ks * 32 + quad * 8);
#pragma unroll
        for (int mt = 0; mt < 4; ++mt) {
            bf16x8 a = *(const bf16x8*)&hid[mt * 16 + col][ks * 32 + quad * 8];
            acc2[mt] = mfma16(a, bb, acc2[mt]);
        }
    }
#pragma unroll
    for (int mt = 0; mt < 4; ++mt)
#pragma unroll
        for (int rg = 0; rg < 4; ++rg) {
            int row = r0 + mt * 16 + quad * 4 + rg;
            int d = w * 16 + col;
            size_t idx = (size_t)row * 128 + d;
            y[idx] = acc2[mt][rg] + bf2f(xb[idx]);
        }
}

extern "C" void kernel_launch(void* const* d_in, const int* in_sizes, int n_in,
                              void* d_out, int out_size, void* d_ws, size_t ws_size,
                              hipStream_t stream)
{
    const float* h_em  = (const float*)d_in[0];
    const float* route = (const float*)d_in[1];
    const float* Wq    = (const float*)d_in[2];
    const float* Wk    = (const float*)d_in[3];
    const float* Wv    = (const float*)d_in[4];
    const float* W_out = (const float*)d_in[5];
    const float* sa_w1 = (const float*)d_in[6];
    const float* sa_b1 = (const float*)d_in[7];
    const float* sa_w2 = (const float*)d_in[8];
    const float* sa_b2 = (const float*)d_in[9];
    const float* ff_w1 = (const float*)d_in[10];
    const float* ff_w2 = (const float*)d_in[11];

    char* ws = (char*)d_ws;
    __hip_bfloat16* Qb    = (__hip_bfloat16*)(ws);
    __hip_bfloat16* Kb    = (__hip_bfloat16*)(ws + 4194304);
    __hip_bfloat16* Vtb   = (__hip_bfloat16*)(ws + 8388608);
    __hip_bfloat16* Wqkvt = (__hip_bfloat16*)(ws + 12582912);
    __hip_bfloat16* Wot   = (__hip_bfloat16*)(ws + 12681216);
    __hip_bfloat16* w1t   = (__hip_bfloat16*)(ws + 12713984);
    __hip_bfloat16* w2t   = (__hip_bfloat16*)(ws + 12845056);
    float*          yv    = (float*)(ws + 12976128);
    __hip_bfloat16* xb    = (__hip_bfloat16*)(ws + 21364736);

    hipLaunchKernelGGL(repack_kernel, dim3(768), dim3(256), 0, stream,
                       Wq, Wk, Wv, W_out, ff_w1, ff_w2, Wqkvt, Wot, w1t, w2t);
    hipLaunchKernelGGL(qkv_kernel, dim3(512), dim3(512), 0, stream,
                       h_em, Wqkvt, Qb, Kb, Vtb);
    hipLaunchKernelGGL(attn_kernel_v4, dim3(2048), dim3(512), 0, stream,
                       Qb, Kb, Vtb, route, sa_w1, sa_b1, sa_w2, sa_b2, h_em, Wot,
                       yv, (float*)d_out);
    hipLaunchKernelGGL(ln_kernel<__hip_bfloat16>, dim3(64), dim3(1024), 0, stream, yv, xb);
    hipLaunchKernelGGL(ff_kernel, dim3(256), dim3(512), 0, stream, xb, w1t, w2t, yv);
    hipLaunchKernelGGL(ln_kernel<float>, dim3(64), dim3(1024), 0, stream,
                       yv, (float*)d_out);
}

// Round 3
// 354.610 us; speedup vs baseline: 1.2685x; 1.0592x over previous
//
#include <hip/hip_runtime.h>
#include <hip/hip_bf16.h>

typedef __bf16 bf16x8 __attribute__((ext_vector_type(8)));
typedef __bf16 bf16x4 __attribute__((ext_vector_type(4)));
typedef float  f32x4  __attribute__((ext_vector_type(4)));

#define DEVI __device__ __forceinline__

DEVI float bf2f(__hip_bfloat16 x) { return __bfloat162float(x); }
DEVI __hip_bfloat16 f2bf(float x) { return __float2bfloat16(x); }

DEVI f32x4 mfma16(bf16x8 a, bf16x8 b, f32x4 c) {
    return __builtin_amdgcn_mfma_f32_16x16x32_bf16(a, b, c, 0, 0, 0);
}

DEVI bf16x8 ld8(const __hip_bfloat16* p) {
    return *reinterpret_cast<const bf16x8*>(p);
}

// convert 8 contiguous fp32 -> bf16x8 fragment (two float4 vector loads)
DEVI bf16x8 cvt8(const float* p) {
    f32x4 u = *reinterpret_cast<const f32x4*>(p);
    f32x4 v = *reinterpret_cast<const f32x4*>(p + 4);
    bf16x8 r;
    r[0] = (__bf16)u[0]; r[1] = (__bf16)u[1]; r[2] = (__bf16)u[2]; r[3] = (__bf16)u[3];
    r[4] = (__bf16)v[0]; r[5] = (__bf16)v[1]; r[6] = (__bf16)v[2]; r[7] = (__bf16)v[3];
    return r;
}

// pack two f32 -> one u32 of 2 bf16 (lo = a, hi = b), RNE
DEVI unsigned cvtpk(float a, float b) {
    unsigned r;
    asm("v_cvt_pk_bf16_f32 %0, %1, %2" : "=v"(r) : "v"(a), "v"(b));
    return r;
}

DEVI bf16x8 u4bf(unsigned x0, unsigned x1, unsigned x2, unsigned x3) {
    union { unsigned u[4]; bf16x8 b; } cv;
    cv.u[0] = x0; cv.u[1] = x1; cv.u[2] = x2; cv.u[3] = x3;
    return cv.b;
}

// zero-extend a 4-elem (k=16-style, k-slot quad*4+j) fragment to the 8-elem
// register shape of the 16x16x32 MFMA. Both A and B use the same slot
// placement and the extra slots are zero on both sides -> exact k=16 MFMA.
DEVI bf16x8 pad4(bf16x4 v) {
    bf16x8 r = {};
    r[0] = v[0]; r[1] = v[1]; r[2] = v[2]; r[3] = v[3];
    return r;
}

// ---------------------------------------------------------------------------
// Sizes: B=64, N=256, D=128, H=8, DK=16, FF=512.  All external I/O fp32.
// ---------------------------------------------------------------------------

// K0: repack fp32 weights into MFMA-B-friendly bf16 layouts (row = out col, contiguous k)
__global__ __launch_bounds__(256) void repack_kernel(
    const float* __restrict__ Wq, const float* __restrict__ Wk,
    const float* __restrict__ Wv, const float* __restrict__ W_out,
    const float* __restrict__ ff_w1, const float* __restrict__ ff_w2,
    __hip_bfloat16* __restrict__ Wqkvt, __hip_bfloat16* __restrict__ Wot,
    __hip_bfloat16* __restrict__ w1t, __hip_bfloat16* __restrict__ w2t)
{
    int t = blockIdx.x * 256 + threadIdx.x;
    if (t < 49152) {                       // Wqkvt[c][d], c = qkv*128 + h*16 + k
        int c = t >> 7, d = t & 127;
        int qkv = c >> 7, h = (c >> 4) & 7, k = c & 15;
        const float* W = (qkv == 0) ? Wq : (qkv == 1) ? Wk : Wv;
        Wqkvt[t] = f2bf(W[(h * 128 + d) * 16 + k]);
    } else if (t < 65536) {                // Wot[d][h*16+v] = W_out[h][v][d]
        int idx = t - 49152;
        int d = idx >> 7, hv = idx & 127, h = hv >> 4, v = hv & 15;
        Wot[idx] = f2bf(W_out[(h * 16 + v) * 128 + d]);
    } else if (t < 131072) {               // w1t[f][d] = ff_w1[d][f]
        int idx = t - 65536;
        int f = idx >> 7, d = idx & 127;
        w1t[idx] = f2bf(ff_w1[d * 512 + f]);
    } else {                               // w2t[d2][f] = ff_w2[f][d2]
        int idx = t - 131072;
        int d2 = idx >> 9, f = idx & 511;
        w2t[idx] = f2bf(ff_w2[f * 128 + d2]);
    }
}

// K1: QKV projection. [16384 x 128] @ [128 x 384] -> Q [b][h][n][k], K [b][h][m][k], Vt [b][h][k][m]
__global__ __launch_bounds__(512) void qkv_kernel(
    const float* __restrict__ hem, const __hip_bfloat16* __restrict__ Wqkvt,
    __hip_bfloat16* __restrict__ Qb, __hip_bfloat16* __restrict__ Kb,
    __hip_bfloat16* __restrict__ Vtb)
{
    const int w = threadIdx.x >> 6, lane = threadIdx.x & 63;
    const int quad = lane >> 4, col = lane & 15;
    const int row0 = blockIdx.x * 32;

    f32x4 acc[2][3] = {};
#pragma unroll
    for (int ks = 0; ks < 4; ++ks) {
        bf16x8 a[2], bb[3];
#pragma unroll
        for (int mt = 0; mt < 2; ++mt)
            a[mt] = cvt8(hem + (size_t)(row0 + mt * 16 + col) * 128 + ks * 32 + quad * 8);
#pragma unroll
        for (int nt = 0; nt < 3; ++nt) {
            int c = (w * 3 + nt) * 16 + col;
            bb[nt] = ld8(Wqkvt + (size_t)c * 128 + ks * 32 + quad * 8);
        }
#pragma unroll
        for (int mt = 0; mt < 2; ++mt)
#pragma unroll
            for (int nt = 0; nt < 3; ++nt)
                acc[mt][nt] = mfma16(a[mt], bb[nt], acc[mt][nt]);
    }
#pragma unroll
    for (int mt = 0; mt < 2; ++mt)
#pragma unroll
        for (int nt = 0; nt < 3; ++nt)
#pragma unroll
            for (int rg = 0; rg < 4; ++rg) {
                int row = row0 + mt * 16 + quad * 4 + rg;
                int c = (w * 3 + nt) * 16 + col;
                int qkv = c >> 7, h = (c >> 4) & 7, k = c & 15;
                int bb_ = row >> 8, n = row & 255;
                __hip_bfloat16 v = f2bf(acc[mt][nt][rg]);
                if (qkv == 0)      Qb[(((size_t)bb_ * 8 + h) * 256 + n) * 16 + k] = v;
                else if (qkv == 1) Kb[(((size_t)bb_ * 8 + h) * 256 + n) * 16 + k] = v;
                else               Vtb[(((size_t)bb_ * 8 + h) * 16 + k) * 256 + n] = v;
            }
}

// K2 v5: fused attention. One block = (b, 8 rows). 512 threads = 8 waves.
// Changes vs v4:
//   - P2 uses exact k=16 MFMAs (zero-filled k-slots 4-7 on BOTH operands of the
//     16x16x32 intrinsic). B1 comes straight from sb/rb as ds_read_b64 (4 ch at
//     k-slot quad*4+j); hidden = relu(c1+b1) is packed in-reg (cvt_pk) directly
//     into MFMA2's B fragment. Zero shuffles, hidden never in LDS.
//   - logits stay in registers (lg[4][16]); softmax reduces per-lane over 16 +
//     shfl_xor within 16 lanes. The f32-logit LDS round-trip is deleted.
//   - bias2 dropped: constant per softmax row -> cancels exactly.
//   - soft written (swizzled) by all waves into per-head slabs -> 4 barriers.
__global__ __launch_bounds__(512, 4) void attn_kernel_v5(
    const __hip_bfloat16* __restrict__ Qb, const __hip_bfloat16* __restrict__ Kb,
    const __hip_bfloat16* __restrict__ Vtb, const float* __restrict__ route,
    const float* __restrict__ sa_w1, const float* __restrict__ sa_b1,
    const float* __restrict__ sa_w2, const float* __restrict__ sa_b2,
    const float* __restrict__ h_em, const __hip_bfloat16* __restrict__ Wot,
    float* __restrict__ y, float* __restrict__ out)
{
    __shared__ alignas(16) __hip_bfloat16 srb[2 * 2048 * 8 + 8];  // sb | 16B pad | rb
    __shared__ alignas(16) __hip_bfloat16 headsb[8][144];
    __shared__ alignas(16) __hip_bfloat16 saw1t16[16][16];
    __shared__ alignas(16) __hip_bfloat16 saw2t16[16][16];
    __shared__ float b1s[16];
    __hip_bfloat16* sb = srb;                // [2048][8] scores ch0-7; later soft slabs
    __hip_bfloat16* rb = srb + 16384 + 8;    // [2048][8] route  ch8-15

    const int tid = threadIdx.x;
    const int w = tid >> 6, lane = tid & 63, quad = lane >> 4, col = lane & 15;
    const int quad4 = quad * 4;
    const int b = blockIdx.x >> 5, tile = blockIdx.x & 31, n0 = tile * 8;
    const f32x4 zero = {0.f, 0.f, 0.f, 0.f};

    {   // P0: stage score_aggr weights in k=16 layout: saw[o][i]
        if (tid < 256) {
            int o = tid >> 4, i = tid & 15;
            saw1t16[o][i] = f2bf(sa_w1[i * 16 + o]);
            saw2t16[o][i] = (o < 8) ? f2bf(sa_w2[i * 8 + o]) : f2bf(0.f);
        }
        if (tid < 16) b1s[tid] = sa_b1[tid];
    }

    {   // P1: route prefetch (scalar) + QK^T scores + route copy/stage
        const int h = w;
        const size_t rbase = (((size_t)h * 64 + b) * 256 + n0) * 256;
        const float* rsrc = route + rbase;
        float rv[32];
#pragma unroll
        for (int r = 0; r < 8; ++r)
#pragma unroll
            for (int j = 0; j < 4; ++j)
                rv[r * 4 + j] = rsrc[r * 256 + j * 64 + lane];

        const __hip_bfloat16* Qh = Qb + ((size_t)(b * 8 + h)) * 256 * 16;
        const __hip_bfloat16* Kh = Kb + ((size_t)(b * 8 + h)) * 256 * 16;
        bf16x8 aq = ld8(Qh + (size_t)(n0 + (col & 7)) * 16 + (quad & 1) * 8);
#pragma unroll
        for (int nt = 0; nt < 16; ++nt) {
            bf16x8 bk = {};
            if (quad < 2) bk = ld8(Kh + (size_t)(nt * 16 + col) * 16 + quad * 8);
            f32x4 c = mfma16(aq, bk, zero);
            if (quad < 2) {
#pragma unroll
                for (int rg = 0; rg < 4; ++rg)
                    sb[((quad * 4 + rg) * 256 + nt * 16 + col) * 8 + h] = f2bf(c[rg]);
            }
        }
        float* rdst = out + 2097152 + rbase;
#pragma unroll
        for (int r = 0; r < 8; ++r)
#pragma unroll
            for (int j = 0; j < 4; ++j) {
                int nm = r * 256 + j * 64 + lane;
                float v = rv[r * 4 + j];
                rdst[nm] = v;                 // fp32 passthrough copy (exact)
                rb[nm * 8 + h] = f2bf(v);     // stage transposed: rows walk stride-1
            }
    }
    __syncthreads();

    float lg[4][16];   // logits: [head rg][t8] (heads quad4..quad4+3; valid quads 0,1)
    {   // P2: score_aggr via exact k=16 MFMAs; hidden AND logits stay in registers
        bf16x8 a1 = pad4(*(const bf16x4*)&saw1t16[col][quad4]);
        bf16x8 a2 = pad4(*(const bf16x4*)&saw2t16[col][quad4]);
        f32x4 bv1 = *(const f32x4*)&b1s[quad4];
        // B1: lane (quad,col) supplies ch quad*4..+3 of row nm: sb ch0-7, rb ch8-15
        const char* aptr = (const char*)((quad & 2) ? rb : sb) + (quad & 1) * 8;
        const int rowbase = (w * 256 + col) * 16;

        bf16x4 b4 = *(const bf16x4*)(aptr + rowbase);
#pragma unroll
        for (int t8 = 0; t8 < 16; ++t8) {
            bf16x8 b1 = pad4(b4);
            if (t8 < 15) b4 = *(const bf16x4*)(aptr + rowbase + (t8 + 1) * 256);
            f32x4 c1 = mfma16(a1, b1, zero);
            unsigned q0 = cvtpk(fmaxf(c1[0] + bv1[0], 0.f), fmaxf(c1[1] + bv1[1], 0.f));
            unsigned q1 = cvtpk(fmaxf(c1[2] + bv1[2], 0.f), fmaxf(c1[3] + bv1[3], 0.f));
            f32x4 c2 = mfma16(a2, u4bf(q0, q1, 0, 0), zero);
#pragma unroll
            for (int rg = 0; rg < 4; ++rg) lg[rg][t8] = c2[rg];
        }
    }

    float inv[4];
    {   // P3 (register-only): softmax over m=256 per (head, n=w); e stored into lg
#pragma unroll
        for (int rg = 0; rg < 4; ++rg) {
            float mx = lg[rg][0];
#pragma unroll
            for (int t = 1; t < 16; ++t) mx = fmaxf(mx, lg[rg][t]);
#pragma unroll
            for (int off = 1; off < 16; off <<= 1) mx = fmaxf(mx, __shfl_xor(mx, off, 64));
            float s = 0.f;
#pragma unroll
            for (int t = 0; t < 16; ++t) {
                float e = __expf(lg[rg][t] - mx);
                lg[rg][t] = e; s += e;
            }
#pragma unroll
            for (int off = 1; off < 16; off <<= 1) s += __shfl_xor(s, off, 64);
            inv[rg] = 1.f / s;
        }
    }
    __syncthreads();   // all P2 reads of sb/rb done before soft overwrites sb

    {   // P3b: write soft bf16 into per-head slabs (XOR-swizzled), quads 0,1 only
        if (quad < 2) {
            const int swz = w << 4;
#pragma unroll
            for (int rg = 0; rg < 4; ++rg) {
                char* slab = (char*)srb + (quad4 + rg) * 4096 + w * 512;
                float iv = inv[rg];
#pragma unroll
                for (int t = 0; t < 16; ++t)
                    *(__hip_bfloat16*)(slab + (((t * 16 + col) * 2) ^ swz)) = f2bf(lg[rg][t] * iv);
            }
        }
    }
    __syncthreads();

    {   // P4: PV (wave w <-> head h=w), soft read through the same swizzle
        const int h = w;
        f32x4 acc = zero;
        const __hip_bfloat16* Vh = Vtb + ((size_t)(b * 8 + h)) * 16 * 256;
        const char* softh = (const char*)srb + h * 4096 + (col & 7) * 512;
        const int sx = (col & 7) << 4;
#pragma unroll
        for (int ks = 0; ks < 8; ++ks) {
            bf16x8 a = *(const bf16x8*)(softh + ((ks * 64 + quad * 16) ^ sx));
            bf16x8 bv = ld8(Vh + (size_t)col * 256 + ks * 32 + quad * 8);
            acc = mfma16(a, bv, acc);
        }
        if (quad < 2) {
#pragma unroll
            for (int rg = 0; rg < 4; ++rg)
                headsb[quad * 4 + rg][h * 16 + col] = f2bf(acc[rg]);
        }
    }
    __syncthreads();

    {   // P5: out-proj + residual -> y (fp32). wave w owns d-tile [w*16, w*16+16)
        f32x4 acc = zero;
#pragma unroll
        for (int ks = 0; ks < 4; ++ks) {
            bf16x8 a = *(const bf16x8*)&headsb[col & 7][ks * 32 + quad * 8];
            bf16x8 bo = ld8(Wot + (size_t)(w * 16 + col) * 128 + ks * 32 + quad * 8);
            acc = mfma16(a, bo, acc);
        }
        if (quad < 2) {
#pragma unroll
            for (int rg = 0; rg < 4; ++rg) {
                int n = n0 + quad * 4 + rg, d = w * 16 + col;
                size_t idx = ((size_t)b * 256 + n) * 128 + d;
                y[idx] = acc[rg] + h_em[idx];
            }
        }
    }
}

// output store helpers for the LN template
DEVI void stout(float* p, float v) { *p = v; }
DEVI void stout(__hip_bfloat16* p, float v) { *p = f2bf(v); }

// K3/K5: per-batch LayerNorm over (n,d) = 32768 elements, unbiased var (/32767)
template<typename OUT>
__global__ __launch_bounds__(1024) void ln_kernel(
    const float* __restrict__ y, OUT* __restrict__ out)
{
    const int b = blockIdx.x;
    const float* yb = y + (size_t)b * 32768;
    float v[32], s = 0.f, sq = 0.f;
#pragma unroll
    for (int j = 0; j < 32; ++j) {
        float x = yb[threadIdx.x + 1024 * j];
        v[j] = x; s += x; sq += x * x;
    }
#pragma unroll
    for (int off = 32; off; off >>= 1) {
        s += __shfl_down(s, off, 64);
        sq += __shfl_down(sq, off, 64);
    }
    __shared__ float ps[16], pq[16], stats[2];
    int wv = threadIdx.x >> 6, ln = threadIdx.x & 63;
    if (ln == 0) { ps[wv] = s; pq[wv] = sq; }
    __syncthreads();
    if (threadIdx.x < 64) {
        float a = (ln < 16) ? ps[ln] : 0.f;
        float bq = (ln < 16) ? pq[ln] : 0.f;
#pragma unroll
        for (int off = 8; off; off >>= 1) {
            a += __shfl_down(a, off, 64);
            bq += __shfl_down(bq, off, 64);
        }
        if (ln == 0) {
            float mean = a * (1.f / 32768.f);
            float var = fmaxf((bq - 32768.f * mean * mean) * (1.f / 32767.f), 0.f);
            stats[0] = mean;
            stats[1] = rsqrtf(var + 1e-5f);
        }
    }
    __syncthreads();
    float mean = stats[0], rstd = stats[1];
    OUT* ob = out + (size_t)b * 32768;
#pragma unroll
    for (int j = 0; j < 32; ++j)
        stout(ob + threadIdx.x + 1024 * j, (v[j] - mean) * rstd);
}

// K4: fused FF: y = relu(x @ w1) @ w2 + x, hidden tile lives in LDS only
// hid padded to [64][520]: 1040B row stride (16B-aligned, !=0 mod 128) ->
// stage-2 A reads (16 rows at fixed col-offset) spread across banks.
__global__ __launch_bounds__(512) void ff_kernel(
    const __hip_bfloat16* __restrict__ xb, const __hip_bfloat16* __restrict__ w1t,
    const __hip_bfloat16* __restrict__ w2t, float* __restrict__ y)
{
    __shared__ alignas(16) __hip_bfloat16 hid[64][520];   // 66.6 KB
    const int w = threadIdx.x >> 6, lane = threadIdx.x & 63;
    const int quad = lane >> 4, col = lane & 15;
    const int r0 = blockIdx.x * 64;

    f32x4 acc[4][4] = {};
#pragma unroll
    for (int ks = 0; ks < 4; ++ks) {
        bf16x8 a[4], bb[4];
#pragma unroll
        for (int mt = 0; mt < 4; ++mt)
            a[mt] = ld8(xb + (size_t)(r0 + mt * 16 + col) * 128 + ks * 32 + quad * 8);
#pragma unroll
        for (int nt = 0; nt < 4; ++nt) {
            int f = (w * 4 + nt) * 16 + col;
            bb[nt] = ld8(w1t + (size_t)f * 128 + ks * 32 + quad * 8);
        }
#pragma unroll
        for (int mt = 0; mt < 4; ++mt)
#pragma unroll
            for (int nt = 0; nt < 4; ++nt)
                acc[mt][nt] = mfma16(a[mt], bb[nt], acc[mt][nt]);
    }
#pragma unroll
    for (int mt = 0; mt < 4; ++mt)
#pragma unroll
        for (int nt = 0; nt < 4; ++nt)
#pragma unroll
            for (int rg = 0; rg < 4; ++rg) {
                int row = mt * 16 + quad * 4 + rg;
                int f = (w * 4 + nt) * 16 + col;
                hid[row][f] = f2bf(fmaxf(acc[mt][nt][rg], 0.f));
            }
    __syncthreads();

    f32x4 acc2[4] = {};
#pragma unroll
    for (int ks = 0; ks < 16; ++ks) {
        bf16x8 bb = ld8(w2t + (size_t)(w * 16 + col) * 512 + ks * 32 + quad * 8);
#pragma unroll
        for (int mt = 0; mt < 4; ++mt) {
            bf16x8 a = *(const bf16x8*)&hid[mt * 16 + col][ks * 32 + quad * 8];
            acc2[mt] = mfma16(a, bb, acc2[mt]);
        }
    }
#pragma unroll
    for (int mt = 0; mt < 4; ++mt)
#pragma unroll
        for (int rg = 0; rg < 4; ++rg) {
            int row = r0 + mt * 16 + quad * 4 + rg;
            int d = w * 16 + col;
            size_t idx = (size_t)row * 128 + d;
            y[idx] = acc2[mt][rg] + bf2f(xb[idx]);
        }
}

extern "C" void kernel_launch(void* const* d_in, const int* in_sizes, int n_in,
                              void* d_out, int out_size, void* d_ws, size_t ws_size,
                              hipStream_t stream)
{
    const float* h_em  = (const float*)d_in[0];
    const float* route = (const float*)d_in[1];
    const float* Wq    = (const float*)d_in[2];
    const float* Wk    = (const float*)d_in[3];
    const float* Wv    = (const float*)d_in[4];
    const float* W_out = (const float*)d_in[5];
    const float* sa_w1 = (const float*)d_in[6];
    const float* sa_b1 = (const float*)d_in[7];
    const float* sa_w2 = (const float*)d_in[8];
    const float* sa_b2 = (const float*)d_in[9];
    const float* ff_w1 = (const float*)d_in[10];
    const float* ff_w2 = (const float*)d_in[11];

    char* ws = (char*)d_ws;
    __hip_bfloat16* Qb    = (__hip_bfloat16*)(ws);
    __hip_bfloat16* Kb    = (__hip_bfloat16*)(ws + 4194304);
    __hip_bfloat16* Vtb   = (__hip_bfloat16*)(ws + 8388608);
    __hip_bfloat16* Wqkvt = (__hip_bfloat16*)(ws + 12582912);
    __hip_bfloat16* Wot   = (__hip_bfloat16*)(ws + 12681216);
    __hip_bfloat16* w1t   = (__hip_bfloat16*)(ws + 12713984);
    __hip_bfloat16* w2t   = (__hip_bfloat16*)(ws + 12845056);
    float*          yv    = (float*)(ws + 12976128);
    __hip_bfloat16* xb    = (__hip_bfloat16*)(ws + 21364736);

    hipLaunchKernelGGL(repack_kernel, dim3(768), dim3(256), 0, stream,
                       Wq, Wk, Wv, W_out, ff_w1, ff_w2, Wqkvt, Wot, w1t, w2t);
    hipLaunchKernelGGL(qkv_kernel, dim3(512), dim3(512), 0, stream,
                       h_em, Wqkvt, Qb, Kb, Vtb);
    hipLaunchKernelGGL(attn_kernel_v5, dim3(2048), dim3(512), 0, stream,
                       Qb, Kb, Vtb, route, sa_w1, sa_b1, sa_w2, sa_b2, h_em, Wot,
                       yv, (float*)d_out);
    hipLaunchKernelGGL(ln_kernel<__hip_bfloat16>, dim3(64), dim3(1024), 0, stream, yv, xb);
    hipLaunchKernelGGL(ff_kernel, dim3(256), dim3(512), 0, stream, xb, w1t, w2t, yv);
    hipLaunchKernelGGL(ln_kernel<float>, dim3(64), dim3(1024), 0, stream,
                       yv, (float*)d_out);
}